// Round 5
// baseline (685.960 us; speedup 1.0000x reference)
//
#include <hip/hip_runtime.h>
#include <hip/hip_bf16.h>

#define DIM 128
#define K 8
#define EPS 1e-8f
#define SQRT_EPS 1e-6f

#define CB 512           // clauses per bucket
#define CSHIFT 9
#define NBMAX 4096       // max buckets (n_clauses/CB = 3907 here)
#define SBLK 1024        // partition blocks
#define MAXSLOT 32       // graph slots per bucket
#define PF 4             // edge-loop pipeline depth

typedef __attribute__((ext_vector_type(8))) short bf16x8;
typedef __attribute__((ext_vector_type(4))) float f32x4;

__device__ inline short bfc(float f) {
    union { __hip_bfloat16 h; short s; } u;
    u.h = __float2bfloat16(f);
    return u.s;
}

#define LDW 136  // padded LDS row (bf16 elements)

// ---------------- MLP via MFMA: logits = relu(x@W1+b1)@W2+b2 -> bf16 ---------
__global__ __launch_bounds__(256) void mlp_kernel(
    const float* __restrict__ x, const float* __restrict__ W1,
    const float* __restrict__ b1, const float* __restrict__ W2,
    const float* __restrict__ b2, unsigned short* __restrict__ lbf, int n_vars)
{
    __shared__ __align__(16) short w1t[DIM][LDW];     // W1^T as bf16 (34.8 KB)
    __shared__ __align__(16) short w2t[16][LDW];      // W2^T (cols 8..15 zero)
    __shared__ __align__(16) short hlds[4][16][LDW];  // per-wave H row-tile

    const int t = threadIdx.x;
    const int wave = t >> 6, lane = t & 63;
    const int lr = lane & 15, lg = lane >> 4;

    for (int i = t; i < DIM * DIM; i += 256) {
        int r = i >> 7, c = i & 127;
        w1t[c][r] = bfc(W1[i]);
    }
    for (int i = t; i < 16 * DIM; i += 256) {
        int c = i >> 7, j = i & 127;
        w2t[c][j] = (c < 8) ? bfc(W2[j * 8 + c]) : (short)0;
    }
    __syncthreads();

    const int rbase = blockIdx.x * 128 + wave * 32;

    bf16x8 a[2][4];
    #pragma unroll
    for (int rt = 0; rt < 2; ++rt) {
        int row = rbase + rt * 16 + lr;
        bool ok = row < n_vars;
        const float* xp = x + (size_t)row * DIM + lg * 8;
        #pragma unroll
        for (int kt = 0; kt < 4; ++kt) {
            bf16x8 av = {0,0,0,0,0,0,0,0};
            if (ok) {
                float4 f0 = *(const float4*)(xp + kt * 32);
                float4 f1 = *(const float4*)(xp + kt * 32 + 4);
                av[0]=bfc(f0.x); av[1]=bfc(f0.y); av[2]=bfc(f0.z); av[3]=bfc(f0.w);
                av[4]=bfc(f1.x); av[5]=bfc(f1.y); av[6]=bfc(f1.z); av[7]=bfc(f1.w);
            }
            a[rt][kt] = av;
        }
    }

    bf16x8 bb[4];
    #pragma unroll
    for (int kt = 0; kt < 4; ++kt)
        bb[kt] = *(const bf16x8*)&w2t[lr][kt * 32 + lg * 8];
    float b2v = (lr < 8) ? b2[lr] : 0.f;

    #pragma unroll
    for (int rt = 0; rt < 2; ++rt) {
        #pragma unroll
        for (int n = 0; n < 8; ++n) {
            f32x4 acc = {0.f, 0.f, 0.f, 0.f};
            #pragma unroll
            for (int kt = 0; kt < 4; ++kt) {
                bf16x8 bf = *(const bf16x8*)&w1t[n * 16 + lr][kt * 32 + lg * 8];
                acc = __builtin_amdgcn_mfma_f32_16x16x32_bf16(a[rt][kt], bf, acc, 0, 0, 0);
            }
            float bcol = b1[n * 16 + lr];
            #pragma unroll
            for (int r = 0; r < 4; ++r) {
                float h = fmaxf(acc[r] + bcol, 0.f);
                hlds[wave][lg * 4 + r][n * 16 + lr] = bfc(h);
            }
        }
        f32x4 acc2 = {0.f, 0.f, 0.f, 0.f};
        #pragma unroll
        for (int kt = 0; kt < 4; ++kt) {
            bf16x8 af = *(const bf16x8*)&hlds[wave][lr][kt * 32 + lg * 8];
            acc2 = __builtin_amdgcn_mfma_f32_16x16x32_bf16(af, bb[kt], acc2, 0, 0, 0);
        }
        if (lr < 8) {
            #pragma unroll
            for (int r = 0; r < 4; ++r) {
                int row = rbase + rt * 16 + lg * 4 + r;
                if (row < n_vars)
                    lbf[(size_t)row * K + lr] = (unsigned short)bfc(acc2[r] + b2v);
            }
        }
    }
}

// ---------------- Pass 0: per-block bucket histogram (LDS only) --------------
__global__ __launch_bounds__(256) void count_kernel(
    const int* __restrict__ ci, unsigned* __restrict__ hist,
    int n_edges, int nb, int tile)
{
    __shared__ unsigned hl[NBMAX];
    const int t = threadIdx.x, b = blockIdx.x;
    for (int i = t; i < nb; i += 256) hl[i] = 0u;
    __syncthreads();
    const int e0 = b * tile, e1 = min(e0 + tile, n_edges);
    for (int e = e0 + t; e < e1; e += 256)
        atomicAdd(&hl[(unsigned)ci[e] >> CSHIFT], 1u);
    __syncthreads();
    for (int i = t; i < nb; i += 256) hist[(size_t)i * SBLK + b] = hl[i];
}

// ---------------- Pass 0b: exclusive scan of each bucket row over blocks -----
__global__ __launch_bounds__(256) void scan1_kernel(
    unsigned* __restrict__ hist, unsigned* __restrict__ btotal)
{
    const int t = threadIdx.x;
    const size_t base = (size_t)blockIdx.x * SBLK + t * 4;
    uint4 v = *(const uint4*)(hist + base);
    unsigned pre0 = 0, pre1 = v.x, pre2 = v.x + v.y, pre3 = v.x + v.y + v.z;
    unsigned run = pre3 + v.w;

    __shared__ unsigned ts[256];
    ts[t] = run;
    __syncthreads();
    for (int off = 1; off < 256; off <<= 1) {
        unsigned xv = (t >= off) ? ts[t - off] : 0u;
        __syncthreads();
        ts[t] += xv;
        __syncthreads();
    }
    unsigned ex = ts[t] - run;
    uint4 o = {ex + pre0, ex + pre1, ex + pre2, ex + pre3};
    *(uint4*)(hist + base) = o;
    if (t == 255) btotal[blockIdx.x] = ts[255];
}

// ---------------- Pass 0c: scan bucket totals -> bucket_base -----------------
__global__ __launch_bounds__(256) void scan2_kernel(
    const unsigned* __restrict__ btotal, unsigned* __restrict__ bbase, int nb)
{
    const int t = threadIdx.x;
    unsigned loc[16];
    unsigned run = 0;
    #pragma unroll
    for (int it = 0; it < 16; ++it) {
        int idx = t * 16 + it;
        unsigned v = (idx < nb) ? btotal[idx] : 0u;
        loc[it] = run;
        run += v;
    }
    __shared__ unsigned ts[256];
    ts[t] = run;
    __syncthreads();
    for (int off = 1; off < 256; off <<= 1) {
        unsigned xv = (t >= off) ? ts[t - off] : 0u;
        __syncthreads();
        ts[t] += xv;
        __syncthreads();
    }
    unsigned ex = ts[t] - run;
    #pragma unroll
    for (int it = 0; it < 16; ++it) {
        int idx = t * 16 + it;
        if (idx <= nb) bbase[idx] = ex + loc[it];
    }
}

// ---------------- Pass 1: scatter packed payloads into bucket regions --------
__global__ __launch_bounds__(256) void scatter_kernel(
    const int* __restrict__ ci, const int* __restrict__ vi,
    const float* __restrict__ pol, const unsigned* __restrict__ hist,
    const unsigned* __restrict__ bbase, unsigned* __restrict__ sorted,
    int n_edges, int nb, int tile)
{
    __shared__ unsigned offs[NBMAX];
    const int t = threadIdx.x, b = blockIdx.x;
    for (int i = t; i < nb; i += 256)
        offs[i] = bbase[i] + hist[(size_t)i * SBLK + b];
    __syncthreads();
    const int e0 = b * tile, e1 = min(e0 + tile, n_edges);
    for (int e = e0 + t; e < e1; e += 256) {
        unsigned c = (unsigned)ci[e];
        unsigned v = (unsigned)vi[e];
        unsigned neg = (pol[e] < 0.f) ? 1u : 0u;
        unsigned pos = atomicAdd(&offs[c >> CSHIFT], 1u);
        sorted[pos] = (c & (CB - 1)) | (v << CSHIFT) | (neg << 28);
    }
}

// ---------------- Pass 2: per-bucket clause reduce + graph fuse --------------
__global__ __launch_bounds__(256) void bucket_kernel(
    const unsigned* __restrict__ sorted, const uint4* __restrict__ logit4,
    const unsigned* __restrict__ bbase, const int* __restrict__ clause_batch,
    float* __restrict__ per_graph, unsigned* __restrict__ gmask,
    int n_clauses, int n_graphs)
{
    __shared__ float acc[K * CB];       // 16 KB, transposed [j][cl] -> bank = cl%32
    __shared__ unsigned cmask[CB];      //  2 KB
    __shared__ float pg[MAXSLOT * K];
    __shared__ unsigned pmask[MAXSLOT];
    __shared__ int sh_ghi;

    const int t = threadIdx.x;
    const int bkt = blockIdx.x;
    const int c_base = bkt << CSHIFT;
    const int n_cl = min(CB, n_clauses - c_base);

    for (int i = t; i < K * CB; i += 256) acc[i] = 0.f;
    for (int i = t; i < CB; i += 256) cmask[i] = 0u;
    for (int i = t; i < MAXSLOT * K; i += 256) pg[i] = 0.f;
    if (t < MAXSLOT) pmask[t] = 0xFFu;
    if (t == 0) sh_ghi = clause_batch[c_base + n_cl - 1];
    __syncthreads();

    const unsigned lo = bbase[bkt], hi = bbase[bkt + 1];

    // 4-deep batched edge loop: issue PF independent payload loads, then PF
    // independent gathers, then process — MLP = PF per wave instead of 1.
    for (unsigned base = lo + t; base < hi; base += 256u * PF) {
        unsigned pay[PF];
        uint4 g[PF];
        #pragma unroll
        for (int u = 0; u < PF; ++u) {
            unsigned e = base + 256u * u;
            pay[u] = (e < hi) ? sorted[e] : 0xFFFFFFFFu;
        }
        #pragma unroll
        for (int u = 0; u < PF; ++u) {
            if (pay[u] != 0xFFFFFFFFu)
                g[u] = logit4[(pay[u] >> CSHIFT) & 0x7FFFF];
        }
        #pragma unroll
        for (int u = 0; u < PF; ++u) {
            if (pay[u] == 0xFFFFFFFFu) continue;
            int cl = pay[u] & (CB - 1);
            unsigned neg = (pay[u] >> 28) & 1u;
            float f[K];
            f[0] = __uint_as_float(g[u].x << 16); f[1] = __uint_as_float(g[u].x & 0xFFFF0000u);
            f[2] = __uint_as_float(g[u].y << 16); f[3] = __uint_as_float(g[u].y & 0xFFFF0000u);
            f[4] = __uint_as_float(g[u].z << 16); f[5] = __uint_as_float(g[u].z & 0xFFFF0000u);
            f[6] = __uint_as_float(g[u].w << 16); f[7] = __uint_as_float(g[u].w & 0xFFFF0000u);
            float sgnv = neg ? -1.f : 1.f;
            unsigned em = 0u;
            #pragma unroll
            for (int j = 0; j < K; ++j) {
                float lit = f[j] * sgnv;
                float sp = fmaxf(lit, 0.f) + __logf(1.f + __expf(-fabsf(lit)));
                atomicAdd(&acc[j * CB + cl], sp);
                em |= ((f[j] > 0.f) != (neg != 0u)) ? (1u << j) : 0u;
            }
            atomicOr(&cmask[cl], em | 0x100u);
        }
    }
    __syncthreads();

    // fold clauses into per-graph slots (register-local accumulation)
    const int g_lo = clause_batch[c_base];
    float lacc[K];
    unsigned land = 0xFFu;
    int cur = -1;
    for (int cl = t; cl < n_cl; cl += 256) {
        int c = c_base + cl;
        int gg = clause_batch[c];
        int slot = gg - g_lo;
        if (slot != cur) {
            if (cur >= 0) {
                if (cur < MAXSLOT) {
                    #pragma unroll
                    for (int j = 0; j < K; ++j) atomicAdd(&pg[cur * K + j], lacc[j]);
                    atomicAnd(&pmask[cur], land);
                } else {
                    #pragma unroll
                    for (int j = 0; j < K; ++j) atomicAdd(&per_graph[(size_t)(g_lo + cur) * K + j], lacc[j]);
                    atomicAnd(&gmask[g_lo + cur], land);
                }
            }
            cur = slot;
            #pragma unroll
            for (int j = 0; j < K; ++j) lacc[j] = 0.f;
            land = 0xFFu;
        }
        unsigned m = cmask[cl];
        unsigned em8 = (m & 0x100u) ? (m & 0xFFu) : 0u;
        land &= em8;
        #pragma unroll
        for (int j = 0; j < K; ++j) {
            float s = acc[j * CB + cl];
            float cv = __expf(-s);
            lacc[j] += cv * (-__logf(1.f - cv + EPS));
        }
    }
    if (cur >= 0) {
        if (cur < MAXSLOT) {
            #pragma unroll
            for (int j = 0; j < K; ++j) atomicAdd(&pg[cur * K + j], lacc[j]);
            atomicAnd(&pmask[cur], land);
        } else {
            #pragma unroll
            for (int j = 0; j < K; ++j) atomicAdd(&per_graph[(size_t)(g_lo + cur) * K + j], lacc[j]);
            atomicAnd(&gmask[g_lo + cur], land);
        }
    }
    __syncthreads();

    const int nslots = min(sh_ghi - g_lo + 1, MAXSLOT);
    if (t < nslots * K) {
        int s = t >> 3, j = t & 7;
        atomicAdd(&per_graph[(size_t)(g_lo + s) * K + j], pg[s * K + j]);
    }
    if (t < nslots) atomicAnd(&gmask[g_lo + t], pmask[t]);
}

// ---------------- Final: per-graph sqrt, sort-8, cost dot, solved ------------
__global__ __launch_bounds__(256) void final_kernel(
    const float* __restrict__ per_graph, const unsigned* __restrict__ gmask,
    int n_graphs, float* __restrict__ out)
{
    const int t = threadIdx.x;
    float dot = 0.f;
    if (t < n_graphs) {
        float v[K];
        #pragma unroll
        for (int j = 0; j < K; ++j)
            v[j] = sqrtf(per_graph[(size_t)t * K + j] + SQRT_EPS) - sqrtf(SQRT_EPS);
        #pragma unroll
        for (int i = 1; i < K; ++i) {
            float key = v[i];
            int j = i - 1;
            while (j >= 0 && v[j] < key) { v[j + 1] = v[j]; --j; }
            v[j + 1] = key;
        }
        #pragma unroll
        for (int i = 0; i < K; ++i)
            dot = fmaf(v[i], (float)((i + 1) * (i + 1)), dot);
        out[1 + t] = (gmask[t] & 0xFFu) ? 1.f : 0.f;
    }
    __shared__ float red[256];
    red[t] = dot;
    __syncthreads();
    for (int s = 128; s >= 1; s >>= 1) {
        if (t < s) red[t] += red[t + s];
        __syncthreads();
    }
    if (t == 0) out[0] = red[0] * (1.f / 204.f);
}

// ---------------------------------------------------------------------------
extern "C" void kernel_launch(void* const* d_in, const int* in_sizes, int n_in,
                              void* d_out, int out_size, void* d_ws, size_t ws_size,
                              hipStream_t stream) {
    const float* x   = (const float*)d_in[0];
    const float* pol = (const float*)d_in[1];
    const int* vi    = (const int*)d_in[2];
    const int* ci    = (const int*)d_in[3];
    const int* cb    = (const int*)d_in[4];
    const float* W1  = (const float*)d_in[5];
    const float* b1  = (const float*)d_in[6];
    const float* W2  = (const float*)d_in[7];
    const float* b2  = (const float*)d_in[8];

    const int n_vars    = in_sizes[0] / DIM;
    const int n_edges   = in_sizes[1];
    const int n_clauses = in_sizes[4];
    const int n_graphs  = out_size - 1;
    const int nb        = (n_clauses + CB - 1) / CB;
    const int tile      = (n_edges + SBLK - 1) / SBLK;

    // ---- workspace layout (256B aligned regions) ----
    char* ws = (char*)d_ws;
    size_t off = 0;
    auto alloc = [&](size_t bytes) { char* p = ws + off; off += (bytes + 255) & ~(size_t)255; return p; };
    unsigned short* lbf = (unsigned short*)alloc((size_t)n_vars * K * 2);  // 8 MB bf16
    unsigned* sorted   = (unsigned*)alloc((size_t)n_edges * 4);            // 24 MB
    unsigned* hist     = (unsigned*)alloc((size_t)NBMAX * SBLK * 4);       // 16 MB
    unsigned* btotal   = (unsigned*)alloc((size_t)NBMAX * 4);
    unsigned* bbase    = (unsigned*)alloc((size_t)(NBMAX + 1) * 4);
    float*    per_graph= (float*)alloc((size_t)n_graphs * K * 4);
    unsigned* gmask    = (unsigned*)alloc((size_t)n_graphs * 4);

    hipMemsetAsync(per_graph, 0, (size_t)n_graphs * K * 4, stream);
    hipMemsetAsync(gmask, 0xFF, (size_t)n_graphs * 4, stream);

    count_kernel<<<SBLK, 256, 0, stream>>>(ci, hist, n_edges, nb, tile);
    scan1_kernel<<<nb, 256, 0, stream>>>(hist, btotal);
    scan2_kernel<<<1, 256, 0, stream>>>(btotal, bbase, nb);
    scatter_kernel<<<SBLK, 256, 0, stream>>>(ci, vi, pol, hist, bbase, sorted,
                                             n_edges, nb, tile);
    mlp_kernel<<<(n_vars + 127) / 128, 256, 0, stream>>>(x, W1, b1, W2, b2, lbf, n_vars);
    bucket_kernel<<<nb, 256, 0, stream>>>(sorted, (const uint4*)lbf, bbase, cb,
                                          per_graph, gmask, n_clauses, n_graphs);
    final_kernel<<<1, 256, 0, stream>>>(per_graph, gmask, n_graphs, (float*)d_out);
}

// Round 6
// 674.877 us; speedup vs baseline: 1.0164x; 1.0164x over previous
//
#include <hip/hip_runtime.h>
#include <hip/hip_bf16.h>

#define DIM 128
#define K 8
#define EPS 1e-8f
#define SQRT_EPS 1e-6f

#define CB 512           // clauses per bucket
#define CSHIFT 9
#define NBMAX 4096       // max buckets (n_clauses/CB = 3907 here)
#define SBLK 1024        // partition blocks
#define MAXSLOT 32       // graph slots per bucket
#define PF 4             // edge-loop pipeline depth

typedef __attribute__((ext_vector_type(8))) short bf16x8;
typedef __attribute__((ext_vector_type(4))) float f32x4;

__device__ inline short bfc(float f) {
    union { __hip_bfloat16 h; short s; } u;
    u.h = __float2bfloat16(f);
    return u.s;
}

#define LDW 136  // padded LDS row (bf16 elements)

// ---------------- MLP via MFMA: logits = relu(x@W1+b1)@W2+b2 -> fp8 ----------
__global__ __launch_bounds__(256) void mlp_kernel(
    const float* __restrict__ x, const float* __restrict__ W1,
    const float* __restrict__ b1, const float* __restrict__ W2,
    const float* __restrict__ b2, uint2* __restrict__ lfp8, int n_vars)
{
    __shared__ __align__(16) short w1t[DIM][LDW];     // W1^T as bf16 (34.8 KB)
    __shared__ __align__(16) short w2t[16][LDW];      // W2^T (cols 8..15 zero)
    __shared__ __align__(16) short hlds[4][16][LDW];  // per-wave H row-tile
    __shared__ __align__(16) float lout[4][32][8];    // per-wave logit rows (4 KB)

    const int t = threadIdx.x;
    const int wave = t >> 6, lane = t & 63;
    const int lr = lane & 15, lg = lane >> 4;

    for (int i = t; i < DIM * DIM; i += 256) {
        int r = i >> 7, c = i & 127;
        w1t[c][r] = bfc(W1[i]);
    }
    for (int i = t; i < 16 * DIM; i += 256) {
        int c = i >> 7, j = i & 127;
        w2t[c][j] = (c < 8) ? bfc(W2[j * 8 + c]) : (short)0;
    }
    __syncthreads();

    const int rbase = blockIdx.x * 128 + wave * 32;

    bf16x8 a[2][4];
    #pragma unroll
    for (int rt = 0; rt < 2; ++rt) {
        int row = rbase + rt * 16 + lr;
        bool ok = row < n_vars;
        const float* xp = x + (size_t)row * DIM + lg * 8;
        #pragma unroll
        for (int kt = 0; kt < 4; ++kt) {
            bf16x8 av = {0,0,0,0,0,0,0,0};
            if (ok) {
                float4 f0 = *(const float4*)(xp + kt * 32);
                float4 f1 = *(const float4*)(xp + kt * 32 + 4);
                av[0]=bfc(f0.x); av[1]=bfc(f0.y); av[2]=bfc(f0.z); av[3]=bfc(f0.w);
                av[4]=bfc(f1.x); av[5]=bfc(f1.y); av[6]=bfc(f1.z); av[7]=bfc(f1.w);
            }
            a[rt][kt] = av;
        }
    }

    bf16x8 bb[4];
    #pragma unroll
    for (int kt = 0; kt < 4; ++kt)
        bb[kt] = *(const bf16x8*)&w2t[lr][kt * 32 + lg * 8];
    float b2v = (lr < 8) ? b2[lr] : 0.f;

    #pragma unroll
    for (int rt = 0; rt < 2; ++rt) {
        #pragma unroll
        for (int n = 0; n < 8; ++n) {
            f32x4 acc = {0.f, 0.f, 0.f, 0.f};
            #pragma unroll
            for (int kt = 0; kt < 4; ++kt) {
                bf16x8 bf = *(const bf16x8*)&w1t[n * 16 + lr][kt * 32 + lg * 8];
                acc = __builtin_amdgcn_mfma_f32_16x16x32_bf16(a[rt][kt], bf, acc, 0, 0, 0);
            }
            float bcol = b1[n * 16 + lr];
            #pragma unroll
            for (int r = 0; r < 4; ++r) {
                float h = fmaxf(acc[r] + bcol, 0.f);
                hlds[wave][lg * 4 + r][n * 16 + lr] = bfc(h);
            }
        }
        f32x4 acc2 = {0.f, 0.f, 0.f, 0.f};
        #pragma unroll
        for (int kt = 0; kt < 4; ++kt) {
            bf16x8 af = *(const bf16x8*)&hlds[wave][lr][kt * 32 + lg * 8];
            acc2 = __builtin_amdgcn_mfma_f32_16x16x32_bf16(af, bb[kt], acc2, 0, 0, 0);
        }
        if (lr < 8) {
            #pragma unroll
            for (int r = 0; r < 4; ++r)
                lout[wave][rt * 16 + lg * 4 + r][lr] = acc2[r] + b2v;
        }
    }

    // pack 8 f32 -> 8 fp8 (e4m3, hardware cvt) per row; lanes 0..31 of each wave
    __syncthreads();
    if (lane < 32) {
        int row = rbase + lane;
        if (row < n_vars) {
            const float* f = lout[wave][lane];
            unsigned lo = 0u, hi = 0u;
            lo = __builtin_amdgcn_cvt_pk_fp8_f32(f[0], f[1], lo, false);
            lo = __builtin_amdgcn_cvt_pk_fp8_f32(f[2], f[3], lo, true);
            hi = __builtin_amdgcn_cvt_pk_fp8_f32(f[4], f[5], hi, false);
            hi = __builtin_amdgcn_cvt_pk_fp8_f32(f[6], f[7], hi, true);
            lfp8[row] = make_uint2(lo, hi);
        }
    }
}

// ---------------- Pass 0: per-block bucket histogram (LDS only) --------------
__global__ __launch_bounds__(256) void count_kernel(
    const int* __restrict__ ci, unsigned* __restrict__ hist,
    int n_edges, int nb, int tile)
{
    __shared__ unsigned hl[NBMAX];
    const int t = threadIdx.x, b = blockIdx.x;
    for (int i = t; i < nb; i += 256) hl[i] = 0u;
    __syncthreads();
    const int e0 = b * tile, e1 = min(e0 + tile, n_edges);
    for (int e = e0 + t; e < e1; e += 256)
        atomicAdd(&hl[(unsigned)ci[e] >> CSHIFT], 1u);
    __syncthreads();
    for (int i = t; i < nb; i += 256) hist[(size_t)i * SBLK + b] = hl[i];
}

// ---------------- Pass 0b: exclusive scan of each bucket row over blocks -----
__global__ __launch_bounds__(256) void scan1_kernel(
    unsigned* __restrict__ hist, unsigned* __restrict__ btotal)
{
    const int t = threadIdx.x;
    const size_t base = (size_t)blockIdx.x * SBLK + t * 4;
    uint4 v = *(const uint4*)(hist + base);
    unsigned pre0 = 0, pre1 = v.x, pre2 = v.x + v.y, pre3 = v.x + v.y + v.z;
    unsigned run = pre3 + v.w;

    __shared__ unsigned ts[256];
    ts[t] = run;
    __syncthreads();
    for (int off = 1; off < 256; off <<= 1) {
        unsigned xv = (t >= off) ? ts[t - off] : 0u;
        __syncthreads();
        ts[t] += xv;
        __syncthreads();
    }
    unsigned ex = ts[t] - run;
    uint4 o = {ex + pre0, ex + pre1, ex + pre2, ex + pre3};
    *(uint4*)(hist + base) = o;
    if (t == 255) btotal[blockIdx.x] = ts[255];
}

// ---------------- Pass 0c: scan bucket totals -> bucket_base -----------------
__global__ __launch_bounds__(256) void scan2_kernel(
    const unsigned* __restrict__ btotal, unsigned* __restrict__ bbase, int nb)
{
    const int t = threadIdx.x;
    unsigned loc[16];
    unsigned run = 0;
    #pragma unroll
    for (int it = 0; it < 16; ++it) {
        int idx = t * 16 + it;
        unsigned v = (idx < nb) ? btotal[idx] : 0u;
        loc[it] = run;
        run += v;
    }
    __shared__ unsigned ts[256];
    ts[t] = run;
    __syncthreads();
    for (int off = 1; off < 256; off <<= 1) {
        unsigned xv = (t >= off) ? ts[t - off] : 0u;
        __syncthreads();
        ts[t] += xv;
        __syncthreads();
    }
    unsigned ex = ts[t] - run;
    #pragma unroll
    for (int it = 0; it < 16; ++it) {
        int idx = t * 16 + it;
        if (idx <= nb) bbase[idx] = ex + loc[it];
    }
}

// ---------------- Pass 1: scatter packed payloads into bucket regions --------
__global__ __launch_bounds__(256) void scatter_kernel(
    const int* __restrict__ ci, const int* __restrict__ vi,
    const float* __restrict__ pol, const unsigned* __restrict__ hist,
    const unsigned* __restrict__ bbase, unsigned* __restrict__ sorted,
    int n_edges, int nb, int tile)
{
    __shared__ unsigned offs[NBMAX];
    const int t = threadIdx.x, b = blockIdx.x;
    for (int i = t; i < nb; i += 256)
        offs[i] = bbase[i] + hist[(size_t)i * SBLK + b];
    __syncthreads();
    const int e0 = b * tile, e1 = min(e0 + tile, n_edges);
    for (int e = e0 + t; e < e1; e += 256) {
        unsigned c = (unsigned)ci[e];
        unsigned v = (unsigned)vi[e];
        unsigned neg = (pol[e] < 0.f) ? 1u : 0u;
        unsigned pos = atomicAdd(&offs[c >> CSHIFT], 1u);
        sorted[pos] = (c & (CB - 1)) | (v << CSHIFT) | (neg << 28);
    }
}

// ---------------- Pass 2: per-bucket clause reduce + graph fuse --------------
__global__ __launch_bounds__(256) void bucket_kernel(
    const unsigned* __restrict__ sorted, const uint2* __restrict__ logit8,
    const unsigned* __restrict__ bbase, const int* __restrict__ clause_batch,
    float* __restrict__ per_graph, unsigned* __restrict__ gmask,
    int n_clauses, int n_graphs)
{
    __shared__ float acc[K * CB];       // 16 KB, transposed [j][cl] -> bank = cl%32
    __shared__ unsigned cmask[CB];      //  2 KB
    __shared__ float pg[MAXSLOT * K];
    __shared__ unsigned pmask[MAXSLOT];
    __shared__ int sh_ghi;

    const int t = threadIdx.x;
    const int bkt = blockIdx.x;
    const int c_base = bkt << CSHIFT;
    const int n_cl = min(CB, n_clauses - c_base);

    for (int i = t; i < K * CB; i += 256) acc[i] = 0.f;
    for (int i = t; i < CB; i += 256) cmask[i] = 0u;
    for (int i = t; i < MAXSLOT * K; i += 256) pg[i] = 0.f;
    if (t < MAXSLOT) pmask[t] = 0xFFu;
    if (t == 0) sh_ghi = clause_batch[c_base + n_cl - 1];
    __syncthreads();

    const unsigned lo = bbase[bkt], hi = bbase[bkt + 1];

    // 4-deep batched edge loop: independent payload loads, then independent
    // 8B fp8 gathers (table = 4 MB -> per-XCD-L2 resident), then process.
    for (unsigned base = lo + t; base < hi; base += 256u * PF) {
        unsigned pay[PF];
        uint2 g[PF];
        #pragma unroll
        for (int u = 0; u < PF; ++u) {
            unsigned e = base + 256u * u;
            pay[u] = (e < hi) ? sorted[e] : 0xFFFFFFFFu;
        }
        #pragma unroll
        for (int u = 0; u < PF; ++u) {
            if (pay[u] != 0xFFFFFFFFu)
                g[u] = logit8[(pay[u] >> CSHIFT) & 0x7FFFF];
        }
        #pragma unroll
        for (int u = 0; u < PF; ++u) {
            if (pay[u] == 0xFFFFFFFFu) continue;
            int cl = pay[u] & (CB - 1);
            unsigned neg = (pay[u] >> 28) & 1u;
            float f[K];
            f[0] = __builtin_amdgcn_cvt_f32_fp8(g[u].x, 0);
            f[1] = __builtin_amdgcn_cvt_f32_fp8(g[u].x, 1);
            f[2] = __builtin_amdgcn_cvt_f32_fp8(g[u].x, 2);
            f[3] = __builtin_amdgcn_cvt_f32_fp8(g[u].x, 3);
            f[4] = __builtin_amdgcn_cvt_f32_fp8(g[u].y, 0);
            f[5] = __builtin_amdgcn_cvt_f32_fp8(g[u].y, 1);
            f[6] = __builtin_amdgcn_cvt_f32_fp8(g[u].y, 2);
            f[7] = __builtin_amdgcn_cvt_f32_fp8(g[u].y, 3);
            float sgnv = neg ? -1.f : 1.f;
            unsigned em = 0u;
            #pragma unroll
            for (int j = 0; j < K; ++j) {
                float lit = f[j] * sgnv;
                float sp = fmaxf(lit, 0.f) + __logf(1.f + __expf(-fabsf(lit)));
                atomicAdd(&acc[j * CB + cl], sp);
                em |= ((f[j] > 0.f) != (neg != 0u)) ? (1u << j) : 0u;
            }
            atomicOr(&cmask[cl], em | 0x100u);
        }
    }
    __syncthreads();

    // fold clauses into per-graph slots (register-local accumulation)
    const int g_lo = clause_batch[c_base];
    float lacc[K];
    unsigned land = 0xFFu;
    int cur = -1;
    for (int cl = t; cl < n_cl; cl += 256) {
        int c = c_base + cl;
        int gg = clause_batch[c];
        int slot = gg - g_lo;
        if (slot != cur) {
            if (cur >= 0) {
                if (cur < MAXSLOT) {
                    #pragma unroll
                    for (int j = 0; j < K; ++j) atomicAdd(&pg[cur * K + j], lacc[j]);
                    atomicAnd(&pmask[cur], land);
                } else {
                    #pragma unroll
                    for (int j = 0; j < K; ++j) atomicAdd(&per_graph[(size_t)(g_lo + cur) * K + j], lacc[j]);
                    atomicAnd(&gmask[g_lo + cur], land);
                }
            }
            cur = slot;
            #pragma unroll
            for (int j = 0; j < K; ++j) lacc[j] = 0.f;
            land = 0xFFu;
        }
        unsigned m = cmask[cl];
        unsigned em8 = (m & 0x100u) ? (m & 0xFFu) : 0u;
        land &= em8;
        #pragma unroll
        for (int j = 0; j < K; ++j) {
            float s = acc[j * CB + cl];
            float cv = __expf(-s);
            lacc[j] += cv * (-__logf(1.f - cv + EPS));
        }
    }
    if (cur >= 0) {
        if (cur < MAXSLOT) {
            #pragma unroll
            for (int j = 0; j < K; ++j) atomicAdd(&pg[cur * K + j], lacc[j]);
            atomicAnd(&pmask[cur], land);
        } else {
            #pragma unroll
            for (int j = 0; j < K; ++j) atomicAdd(&per_graph[(size_t)(g_lo + cur) * K + j], lacc[j]);
            atomicAnd(&gmask[g_lo + cur], land);
        }
    }
    __syncthreads();

    const int nslots = min(sh_ghi - g_lo + 1, MAXSLOT);
    if (t < nslots * K) {
        int s = t >> 3, j = t & 7;
        atomicAdd(&per_graph[(size_t)(g_lo + s) * K + j], pg[s * K + j]);
    }
    if (t < nslots) atomicAnd(&gmask[g_lo + t], pmask[t]);
}

// ---------------- Final: per-graph sqrt, sort-8, cost dot, solved ------------
__global__ __launch_bounds__(256) void final_kernel(
    const float* __restrict__ per_graph, const unsigned* __restrict__ gmask,
    int n_graphs, float* __restrict__ out)
{
    const int t = threadIdx.x;
    float dot = 0.f;
    if (t < n_graphs) {
        float v[K];
        #pragma unroll
        for (int j = 0; j < K; ++j)
            v[j] = sqrtf(per_graph[(size_t)t * K + j] + SQRT_EPS) - sqrtf(SQRT_EPS);
        #pragma unroll
        for (int i = 1; i < K; ++i) {
            float key = v[i];
            int j = i - 1;
            while (j >= 0 && v[j] < key) { v[j + 1] = v[j]; --j; }
            v[j + 1] = key;
        }
        #pragma unroll
        for (int i = 0; i < K; ++i)
            dot = fmaf(v[i], (float)((i + 1) * (i + 1)), dot);
        out[1 + t] = (gmask[t] & 0xFFu) ? 1.f : 0.f;
    }
    __shared__ float red[256];
    red[t] = dot;
    __syncthreads();
    for (int s = 128; s >= 1; s >>= 1) {
        if (t < s) red[t] += red[t + s];
        __syncthreads();
    }
    if (t == 0) out[0] = red[0] * (1.f / 204.f);
}

// ---------------------------------------------------------------------------
extern "C" void kernel_launch(void* const* d_in, const int* in_sizes, int n_in,
                              void* d_out, int out_size, void* d_ws, size_t ws_size,
                              hipStream_t stream) {
    const float* x   = (const float*)d_in[0];
    const float* pol = (const float*)d_in[1];
    const int* vi    = (const int*)d_in[2];
    const int* ci    = (const int*)d_in[3];
    const int* cb    = (const int*)d_in[4];
    const float* W1  = (const float*)d_in[5];
    const float* b1  = (const float*)d_in[6];
    const float* W2  = (const float*)d_in[7];
    const float* b2  = (const float*)d_in[8];

    const int n_vars    = in_sizes[0] / DIM;
    const int n_edges   = in_sizes[1];
    const int n_clauses = in_sizes[4];
    const int n_graphs  = out_size - 1;
    const int nb        = (n_clauses + CB - 1) / CB;
    const int tile      = (n_edges + SBLK - 1) / SBLK;

    // ---- workspace layout (256B aligned regions) ----
    char* ws = (char*)d_ws;
    size_t off = 0;
    auto alloc = [&](size_t bytes) { char* p = ws + off; off += (bytes + 255) & ~(size_t)255; return p; };
    uint2*    lfp8     = (uint2*)alloc((size_t)n_vars * 8);                // 4 MB fp8
    unsigned* sorted   = (unsigned*)alloc((size_t)n_edges * 4);            // 24 MB
    unsigned* hist     = (unsigned*)alloc((size_t)NBMAX * SBLK * 4);       // 16 MB
    unsigned* btotal   = (unsigned*)alloc((size_t)NBMAX * 4);
    unsigned* bbase    = (unsigned*)alloc((size_t)(NBMAX + 1) * 4);
    float*    per_graph= (float*)alloc((size_t)n_graphs * K * 4);
    unsigned* gmask    = (unsigned*)alloc((size_t)n_graphs * 4);

    hipMemsetAsync(per_graph, 0, (size_t)n_graphs * K * 4, stream);
    hipMemsetAsync(gmask, 0xFF, (size_t)n_graphs * 4, stream);

    count_kernel<<<SBLK, 256, 0, stream>>>(ci, hist, n_edges, nb, tile);
    scan1_kernel<<<nb, 256, 0, stream>>>(hist, btotal);
    scan2_kernel<<<1, 256, 0, stream>>>(btotal, bbase, nb);
    scatter_kernel<<<SBLK, 256, 0, stream>>>(ci, vi, pol, hist, bbase, sorted,
                                             n_edges, nb, tile);
    mlp_kernel<<<(n_vars + 127) / 128, 256, 0, stream>>>(x, W1, b1, W2, b2, lfp8, n_vars);
    bucket_kernel<<<nb, 256, 0, stream>>>(sorted, lfp8, bbase, cb,
                                          per_graph, gmask, n_clauses, n_graphs);
    final_kernel<<<1, 256, 0, stream>>>(per_graph, gmask, n_graphs, (float*)d_out);
}